// Round 6
// baseline (759.917 us; speedup 1.0000x reference)
//
#include <hip/hip_runtime.h>
#include <hip/hip_bf16.h>
#include <math.h>

#define NN 100000
#define EE 1600000
#define DIN 384
#define HD 128
#define HHD 64
#define NRL 4
#define BN_EPS 1e-5f
#define SB 98     // scan/sort blocks: 98*1024 >= NN
#define NBUK 49   // dst buckets (dst>>11), 2048 nodes each
#define EB 391    // edge blocks: 391*4096 >= EE
#define EPB 4096  // edges per block in bucket passes

typedef _Float16 half8 __attribute__((ext_vector_type(8)));
typedef float floatx4 __attribute__((ext_vector_type(4)));

// async global->LDS 16B: LDS dest = wave-uniform base + lane*16
__device__ __forceinline__ void async_cp16(const _Float16* g, _Float16* l) {
    __builtin_amdgcn_global_load_lds((const __attribute__((address_space(1))) void*)g,
                                     (__attribute__((address_space(3))) void*)l, 16, 0, 0);
}

// ---------------- fp32 -> fp16 convert (streaming) ----------------
__global__ void cvt_k(const float* __restrict__ x, _Float16* __restrict__ xh, int n8) {
    int i = blockIdx.x * blockDim.x + threadIdx.x;
    if (i < n8) {
        float4 u = *(const float4*)(x + (size_t)i * 8);
        float4 v = *(const float4*)(x + (size_t)i * 8 + 4);
        half8 h = {(_Float16)u.x, (_Float16)u.y, (_Float16)u.z, (_Float16)u.w,
                   (_Float16)v.x, (_Float16)v.y, (_Float16)v.z, (_Float16)v.w};
        *(half8*)(xh + (size_t)i * 8) = h;
    }
}

// ---------------- CSR build ----------------
__global__ void zero_k(int* __restrict__ cnt) {
    int i = blockIdx.x * blockDim.x + threadIdx.x;
    if (i < NN) cnt[i] = 0;
}

// fused: per-node degree histogram + per-(bucket,block) counts
__global__ __launch_bounds__(256) void histb_k(const int* __restrict__ dst,
                                               int* __restrict__ cnt,
                                               int* __restrict__ blockHist) {
    __shared__ int h[NBUK];
    int t = threadIdx.x;
    if (t < NBUK) h[t] = 0;
    __syncthreads();
    int base = blockIdx.x * EPB;
#pragma unroll
    for (int i = 0; i < 16; ++i) {
        int e = base + i * 256 + t;
        if (e < EE) {
            int d = dst[e];
            atomicAdd(&cnt[d], 1);
            atomicAdd(&h[d >> 11], 1);
        }
    }
    __syncthreads();
    if (t < NBUK) blockHist[t * EB + blockIdx.x] = h[t];   // bucket-major
}

// exclusive scan of NBUK*EB counts -> ebase; bucket bounds -> bo[NBUK+1]
__global__ __launch_bounds__(1024) void ebscan_k(const int* __restrict__ blockHist,
                                                 int* __restrict__ ebase,
                                                 int* __restrict__ bo) {
    __shared__ int sums[1024];
    const int TOT = NBUK * EB;
    int t = threadIdx.x;
    const int chunk = (TOT + 1023) / 1024;
    int lo = t * chunk, hi = min(lo + chunk, TOT);
    int s = 0;
    for (int i = lo; i < hi; ++i) s += blockHist[i];
    sums[t] = s;
    __syncthreads();
    for (int off = 1; off < 1024; off <<= 1) {
        int v = (t >= off) ? sums[t - off] : 0;
        __syncthreads();
        sums[t] += v;
        __syncthreads();
    }
    int run = (t == 0) ? 0 : sums[t - 1];
    for (int i = lo; i < hi; ++i) { ebase[i] = run; run += blockHist[i]; }
    __syncthreads();
    if (t < NBUK) bo[t] = ebase[t * EB];
    if (t == NBUK) bo[NBUK] = EE;
}

// scatter (src,dst) into contiguous per-(bucket,block) streams
__global__ __launch_bounds__(256) void ebfill_k(const int* __restrict__ src,
                                                const int* __restrict__ dst,
                                                const int* __restrict__ ebase,
                                                int2* __restrict__ ebuf) {
    __shared__ int loff[NBUK];
    int t = threadIdx.x;
    if (t < NBUK) loff[t] = ebase[t * EB + blockIdx.x];
    __syncthreads();
    int base = blockIdx.x * EPB;
#pragma unroll
    for (int i = 0; i < 16; ++i) {
        int e = base + i * 256 + t;
        if (e < EE) {
            int sv = src[e], d = dst[e];
            int p = atomicAdd(&loff[d >> 11], 1);
            ebuf[p] = make_int2(sv, d);
        }
    }
}

// one block per bucket: LDS fill counters, col writes stay in an L2-resident window
__global__ __launch_bounds__(1024) void cfill_k(const int2* __restrict__ ebuf,
                                                const int* __restrict__ bo,
                                                const int* __restrict__ rowptr,
                                                int* __restrict__ col) {
    __shared__ int lfill[2048];
    int t = threadIdx.x;
    lfill[t] = 0;
    lfill[t + 1024] = 0;
    __syncthreads();
    int b = blockIdx.x;
    int lo = bo[b], hi = bo[b + 1];
    int nodeBase = b << 11;
    for (int j = lo + t; j < hi; j += 1024) {
        int2 e = ebuf[j];
        int p = atomicAdd(&lfill[e.y - nodeBase], 1);
        col[rowptr[e.y] + p] = e.x;
    }
}

// ---- 3-phase parallel exclusive scan of cnt -> rowptr (+dinv) ----
__global__ __launch_bounds__(1024) void rscan1_k(const int* __restrict__ cnt,
                                                 int* __restrict__ rowptr,
                                                 float* __restrict__ dinv,
                                                 int* __restrict__ blockSum) {
    __shared__ int wsum[16];
    int t = threadIdx.x;
    int i = blockIdx.x * 1024 + t;
    int v = (i < NN) ? cnt[i] : 0;
    int lane = t & 63;
    int wid = t >> 6;
    int x = v;
#pragma unroll
    for (int off = 1; off < 64; off <<= 1) {
        int y = __shfl_up(x, off, 64);
        if (lane >= off) x += y;
    }
    if (lane == 63) wsum[wid] = x;
    __syncthreads();
    if (wid == 0) {
        int s = (lane < 16) ? wsum[lane] : 0;
#pragma unroll
        for (int off = 1; off < 16; off <<= 1) {
            int y = __shfl_up(s, off, 64);
            if (lane >= off) s += y;
        }
        if (lane < 16) wsum[lane] = s;
    }
    __syncthreads();
    int excl = x - v + (wid > 0 ? wsum[wid - 1] : 0);
    if (i < NN) {
        rowptr[i] = excl;
        dinv[i] = rsqrtf((float)v + 1.0f);
    }
    if (t == 1023) blockSum[blockIdx.x] = excl + v;
}

__global__ void rscan2_k(const int* __restrict__ blockSum, int* __restrict__ blockOff) {
    __shared__ int s[SB + 1];
    int t = threadIdx.x;
    if (t < SB) s[t] = blockSum[t];
    __syncthreads();
    if (t == 0) {
        int run = 0;
        for (int i = 0; i < SB; ++i) { int c = s[i]; s[i] = run; run += c; }
        s[SB] = run;
    }
    __syncthreads();
    if (t <= SB) blockOff[t] = s[t];
}

__global__ __launch_bounds__(1024) void rscan3_k(int* __restrict__ rowptr,
                                                 const int* __restrict__ blockOff) {
    int i = blockIdx.x * 1024 + threadIdx.x;
    if (i < NN) rowptr[i] += blockOff[blockIdx.x];
    if (i == 0) rowptr[NN] = blockOff[SB];
}

// ---------------- degree counting sort (LDS histograms) ----------------
__global__ __launch_bounds__(1024) void bhist2_k(const int* __restrict__ cnt,
                                                 int* __restrict__ blockHist) {
    __shared__ int h[64];
    int t = threadIdx.x;
    if (t < 64) h[t] = 0;
    __syncthreads();
    int n = blockIdx.x * 1024 + t;
    if (n < NN) atomicAdd(&h[min(cnt[n], 63)], 1);
    __syncthreads();
    if (t < 64) blockHist[t * SB + blockIdx.x] = h[t];
}

__global__ __launch_bounds__(1024) void bscan2_k(const int* __restrict__ blockHist,
                                                 int* __restrict__ blockBase) {
    __shared__ int sums[1024];
    const int TOT = 64 * SB;
    int t = threadIdx.x;
    const int chunk = (TOT + 1023) / 1024;
    int lo = t * chunk, hi = min(lo + chunk, TOT);
    int s = 0;
    for (int i = lo; i < hi; ++i) s += blockHist[i];
    sums[t] = s;
    __syncthreads();
    for (int off = 1; off < 1024; off <<= 1) {
        int v = (t >= off) ? sums[t - off] : 0;
        __syncthreads();
        sums[t] += v;
        __syncthreads();
    }
    int run = (t == 0) ? 0 : sums[t - 1];
    for (int i = lo; i < hi; ++i) {
        blockBase[i] = run;
        run += blockHist[i];
    }
}

__global__ __launch_bounds__(1024) void bfill2_k(const int* __restrict__ cnt,
                                                 const int* __restrict__ blockBase,
                                                 int* __restrict__ perm) {
    __shared__ int off[64];
    int t = threadIdx.x;
    if (t < 64) off[t] = blockBase[t * SB + blockIdx.x];
    __syncthreads();
    int n = blockIdx.x * 1024 + t;
    if (n < NN) {
        int b = min(cnt[n], 63);
        int p = atomicAdd(&off[b], 1);
        perm[p] = n;
    }
}

// ---------------- pack weight B[K][N] (row-major fp32) into MFMA fragment layout fp16 ----------------
__global__ void pack_frag_k(const float* __restrict__ B, _Float16* __restrict__ out,
                            int K, int N) {
    int t = blockIdx.x * blockDim.x + threadIdx.x;
    if (t >= K * N) return;
    int j = t & 7;
    int lane = (t >> 3) & 63;
    int rest = t >> 9;
    int NT = N >> 4;
    int nt = rest % NT;
    int kc = rest / NT;
    int k = kc * 32 + (lane >> 4) * 8 + j;
    int c = nt * 16 + (lane & 15);
    out[t] = (_Float16)B[(size_t)k * N + c];
}

// pack the three head W1s into frag layout for N=192, plus bias
__global__ void pack_heads_k(const float* __restrict__ relW1, const float* __restrict__ rsW1,
                             const float* __restrict__ rlW1, const float* __restrict__ relb1,
                             const float* __restrict__ rsb1, const float* __restrict__ rlb1,
                             _Float16* __restrict__ out, float* __restrict__ b1p) {
    int t = blockIdx.x * blockDim.x + threadIdx.x;
    if (t < HD * 192) {
        int j = t & 7;
        int lane = (t >> 3) & 63;
        int rest = t >> 9;
        const int NT = 12;
        int nt = rest % NT;
        int kc = rest / NT;
        int k = kc * 32 + (lane >> 4) * 8 + j;
        int c = nt * 16 + (lane & 15);
        int s = c >> 6, jj = c & 63;
        float v = (s == 0) ? relW1[k * HHD + jj] : (s == 1) ? rsW1[k * HHD + jj] : rlW1[k * HHD + jj];
        out[t] = (_Float16)v;
    }
    if (t < 192) {
        int s = t >> 6, jj = t & 63;
        b1p[t] = (s == 0) ? relb1[jj] : (s == 1) ? rsb1[jj] : rlb1[jj];
    }
}

// ---------------- MFMA GEMM with async-LDS double buffer ----------------
template<int K, int MODE>
__global__ __launch_bounds__(256) void mgemm2_k(const _Float16* __restrict__ A,
                                                const _Float16* __restrict__ Bp,
                                                const float* __restrict__ bias,
                                                const float* __restrict__ dinv,
                                                _Float16* __restrict__ C) {
    constexpr int NC = K / 64;
    const int NT = 8;
    __shared__ _Float16 As[2][64 * 64];
    const int tid = threadIdx.x;
    const int w = tid >> 6;
    const int L = tid & 63;
    const int q = L >> 4;
    const int l16 = L & 15;
    const int row0 = blockIdx.x * 64;

    const int r8 = L >> 3;
    const int scol = ((L & 7) ^ r8) * 8;
    const size_t srow0 = (size_t)min(row0 + w * 8 + r8, NN - 1) * K;
    const size_t srow1 = (size_t)min(row0 + 32 + w * 8 + r8, NN - 1) * K;
    _Float16* lds0a = &As[0][w * 512];
    _Float16* lds0b = &As[0][(4 + w) * 512];
    _Float16* lds1a = &As[1][w * 512];
    _Float16* lds1b = &As[1][(4 + w) * 512];

    floatx4 acc[NT];
#pragma unroll
    for (int nt = 0; nt < NT; ++nt) acc[nt] = (floatx4){0.f, 0.f, 0.f, 0.f};

    const half8* __restrict__ bp8 = (const half8*)Bp;
    const int rs = l16 & 7;
    const int gsel = (w * 2 + (l16 >> 3)) * 512 + rs * 64;

    async_cp16(A + srow0 + scol, lds0a);
    async_cp16(A + srow1 + scol, lds0b);
    __syncthreads();

    for (int kc = 0; kc < NC; ++kc) {
        if (kc + 1 < NC) {
            if ((kc & 1) == 0) {
                async_cp16(A + srow0 + (kc + 1) * 64 + scol, lds1a);
                async_cp16(A + srow1 + (kc + 1) * 64 + scol, lds1b);
            } else {
                async_cp16(A + srow0 + (kc + 1) * 64 + scol, lds0a);
                async_cp16(A + srow1 + (kc + 1) * 64 + scol, lds0b);
            }
        }
        const _Float16* cur = As[kc & 1];
#pragma unroll
        for (int kk = 0; kk < 2; ++kk) {
            int chunk = kk * 4 + q;
            half8 a = *(const half8*)(cur + gsel + ((chunk ^ rs) * 8));
#pragma unroll
            for (int nt = 0; nt < NT; ++nt) {
                half8 b = bp8[(size_t)((kc * 2 + kk) * NT + nt) * 64 + L];
                acc[nt] = __builtin_amdgcn_mfma_f32_16x16x32_f16(a, b, acc[nt], 0, 0, 0);
            }
        }
        __syncthreads();
    }

#pragma unroll
    for (int r = 0; r < 4; ++r) {
        int row = row0 + w * 16 + q * 4 + r;
        if (row >= NN) continue;
        if (MODE == 0) {
#pragma unroll
            for (int nt = 0; nt < NT; ++nt) {
                int c = nt * 16 + l16;
                C[(size_t)row * HD + c] = (_Float16)fmaxf(acc[nt][r] + bias[c], 0.f);
            }
        } else {
            float dv = dinv[row];
#pragma unroll
            for (int nt = 0; nt < NT; ++nt) {
                int c = nt * 16 + l16;
                C[(size_t)row * HD + c] = (_Float16)(acc[nt][r] * dv);
            }
        }
    }
}

// ---------------- aggregation + BN + relu + residual (fp16 gather, 8-deep) ----------------
__global__ __launch_bounds__(256) void agg_k(const _Float16* __restrict__ hws,
                                             const _Float16* __restrict__ h_in,
                                             _Float16* __restrict__ h_out,
                                             const float* __restrict__ dinv,
                                             const int* __restrict__ rowptr,
                                             const int* __restrict__ col,
                                             const int* __restrict__ perm,
                                             const float* __restrict__ bcv,
                                             const float* __restrict__ gamma,
                                             const float* __restrict__ beta,
                                             const float* __restrict__ rmean,
                                             const float* __restrict__ rvar,
                                             int residual) {
    int g = blockIdx.x * 16 + (threadIdx.x >> 4);
    if (g >= NN) return;
    int node = perm[g];
    int l = threadIdx.x & 15;
    int f0 = l * 8;

    int lo = rowptr[node], hi = rowptr[node + 1];

    half8 vself = *(const half8*)(hws + (size_t)node * HD + f0);
    half8 hin;
    if (residual) hin = *(const half8*)(h_in + (size_t)node * HD + f0);

    float acc[8];
#pragma unroll
    for (int i = 0; i < 8; ++i) acc[i] = 0.f;

    int j = lo;
    for (; j + 7 < hi; j += 8) {
        half8 v0 = *(const half8*)(hws + (size_t)col[j]     * HD + f0);
        half8 v1 = *(const half8*)(hws + (size_t)col[j + 1] * HD + f0);
        half8 v2 = *(const half8*)(hws + (size_t)col[j + 2] * HD + f0);
        half8 v3 = *(const half8*)(hws + (size_t)col[j + 3] * HD + f0);
        half8 v4 = *(const half8*)(hws + (size_t)col[j + 4] * HD + f0);
        half8 v5 = *(const half8*)(hws + (size_t)col[j + 5] * HD + f0);
        half8 v6 = *(const half8*)(hws + (size_t)col[j + 6] * HD + f0);
        half8 v7 = *(const half8*)(hws + (size_t)col[j + 7] * HD + f0);
#pragma unroll
        for (int i = 0; i < 8; ++i)
            acc[i] += (((float)v0[i] + (float)v1[i]) + ((float)v2[i] + (float)v3[i])) +
                      (((float)v4[i] + (float)v5[i]) + ((float)v6[i] + (float)v7[i]));
    }
    for (; j + 3 < hi; j += 4) {
        half8 v0 = *(const half8*)(hws + (size_t)col[j]     * HD + f0);
        half8 v1 = *(const half8*)(hws + (size_t)col[j + 1] * HD + f0);
        half8 v2 = *(const half8*)(hws + (size_t)col[j + 2] * HD + f0);
        half8 v3 = *(const half8*)(hws + (size_t)col[j + 3] * HD + f0);
#pragma unroll
        for (int i = 0; i < 8; ++i)
            acc[i] += ((float)v0[i] + (float)v1[i]) + ((float)v2[i] + (float)v3[i]);
    }
    for (; j < hi; ++j) {
        half8 v0 = *(const half8*)(hws + (size_t)col[j] * HD + f0);
#pragma unroll
        for (int i = 0; i < 8; ++i) acc[i] += (float)v0[i];
    }
#pragma unroll
    for (int i = 0; i < 8; ++i) acc[i] += (float)vself[i];

    float dv = dinv[node];
    half8 outv;
#pragma unroll
    for (int i = 0; i < 8; ++i) {
        int f = f0 + i;
        float pre = dv * acc[i] + bcv[f];
        float scale = gamma[f] * rsqrtf(rvar[f] + BN_EPS);
        float v = (pre - rmean[f]) * scale + beta[f];
        v = fmaxf(v, 0.f);
        if (residual) v += (float)hin[i];
        outv[i] = (_Float16)v;
    }
    *(half8*)(h_out + (size_t)node * HD + f0) = outv;
}

// ---------------- fused heads ----------------
__global__ __launch_bounds__(256) void heads_k(const _Float16* __restrict__ hfin,
                                               const _Float16* __restrict__ W1P,
                                               const float* __restrict__ b1p,
                                               const float* __restrict__ relW2, const float* __restrict__ relb2,
                                               const float* __restrict__ rsW2,  const float* __restrict__ rsb2,
                                               const float* __restrict__ rlW2,  const float* __restrict__ rlb2,
                                               float* __restrict__ out) {
    __shared__ float Hs[64 * 196];
#define HS(r, c) Hs[(r) * 196 + (c)]
    const int NT = 12;
    const int tid = threadIdx.x;
    const int w = tid >> 6;
    const int L = tid & 63;
    const int q = L >> 4;
    const int l16 = L & 15;
    const int row0 = blockIdx.x * 64 + w * 16;

    floatx4 acc[NT];
#pragma unroll
    for (int nt = 0; nt < NT; ++nt) acc[nt] = (floatx4){0.f, 0.f, 0.f, 0.f};

    const half8* __restrict__ bp8 = (const half8*)W1P;
    const half8 hz = {(_Float16)0, (_Float16)0, (_Float16)0, (_Float16)0,
                      (_Float16)0, (_Float16)0, (_Float16)0, (_Float16)0};
    const int r0 = row0 + l16;

#pragma unroll
    for (int kc = 0; kc < HD / 32; ++kc) {
        half8 a = (r0 < NN) ? *(const half8*)(hfin + (size_t)r0 * HD + kc * 32 + q * 8) : hz;
#pragma unroll
        for (int nt = 0; nt < NT; ++nt) {
            half8 b = bp8[(size_t)(kc * NT + nt) * 64 + L];
            acc[nt] = __builtin_amdgcn_mfma_f32_16x16x32_f16(a, b, acc[nt], 0, 0, 0);
        }
    }

#pragma unroll
    for (int nt = 0; nt < NT; ++nt) {
        int c = nt * 16 + l16;
        float bb = b1p[c];
#pragma unroll
        for (int r = 0; r < 4; ++r)
            HS(w * 16 + q * 4 + r, c) = fmaxf(acc[nt][r] + bb, 0.f);
    }
    __syncthreads();

    for (int t = tid; t < 64 * 6; t += 256) {
        int row = t & 63;
        int o = t >> 6;
        int grow = blockIdx.x * 64 + row;
        if (grow >= NN) continue;
        if (o == 0) {
            float s = 0.f;
#pragma unroll
            for (int jj = 0; jj < 64; ++jj) s += HS(row, 64 + jj) * rsW2[jj];
            out[grow] = 1.f / (1.f + expf(-(s + rsb2[0])));
        } else if (o <= 4) {
            int c = o - 1;
            float s = 0.f;
#pragma unroll
            for (int jj = 0; jj < 64; ++jj) s += HS(row, 128 + jj) * rlW2[jj * NRL + c];
            out[NN + (size_t)grow * NRL + c] = s + rlb2[c];
        } else {
            float s = 0.f;
#pragma unroll
            for (int jj = 0; jj < 64; ++jj) s += HS(row, jj) * relW2[jj];
            out[NN * (1 + NRL) + grow] = 1.f / (1.f + expf(-(s + relb2[0])));
        }
    }
#undef HS
}

extern "C" void kernel_launch(void* const* d_in, const int* in_sizes, int n_in,
                              void* d_out, int out_size, void* d_ws, size_t ws_size,
                              hipStream_t stream) {
    const float* x     = (const float*)d_in[0];
    const int*   ei    = (const int*)d_in[1];
    const float* Wp    = (const float*)d_in[2];
    const float* bp    = (const float*)d_in[3];
    const float* Wc    = (const float*)d_in[4];
    const float* bc    = (const float*)d_in[5];
    const float* gamma = (const float*)d_in[6];
    const float* beta  = (const float*)d_in[7];
    const float* rmean = (const float*)d_in[8];
    const float* rvar  = (const float*)d_in[9];
    const float* relW1 = (const float*)d_in[10];
    const float* relb1 = (const float*)d_in[11];
    const float* relW2 = (const float*)d_in[12];
    const float* relb2 = (const float*)d_in[13];
    const float* rsW1  = (const float*)d_in[14];
    const float* rsb1  = (const float*)d_in[15];
    const float* rsW2  = (const float*)d_in[16];
    const float* rsb2  = (const float*)d_in[17];
    const float* rlW1  = (const float*)d_in[18];
    const float* rlb1  = (const float*)d_in[19];
    const float* rlW2  = (const float*)d_in[20];
    const float* rlb2  = (const float*)d_in[21];
    float* out = (float*)d_out;

    char* w = (char*)d_ws;
    _Float16* xh  = (_Float16*)w; w += (size_t)NN * DIN * 2;
    _Float16* h0  = (_Float16*)w; w += (size_t)NN * HD * 2;
    _Float16* h1  = (_Float16*)w; w += (size_t)NN * HD * 2;
    _Float16* hws = (_Float16*)w; w += (size_t)NN * HD * 2;
    _Float16* WpP = (_Float16*)w; w += (size_t)DIN * HD * 2;
    _Float16* WcP = (_Float16*)w; w += (size_t)3 * HD * HD * 2;
    _Float16* W1P = (_Float16*)w; w += (size_t)HD * 192 * 2;
    float* b1p    = (float*)w;    w += 256 * 4;
    float* dinv   = (float*)w;    w += (size_t)NN * 4;
    int* rowptr   = (int*)w;      w += (size_t)(NN + 4) * 4;
    int* col      = (int*)w;      w += (size_t)EE * 4;
    int* cnt      = (int*)w;      w += (size_t)NN * 4;
    int* perm     = (int*)w;      w += (size_t)NN * 4;
    int* bHist    = (int*)w;      w += (size_t)64 * SB * 4;
    int* bBase    = (int*)w;      w += (size_t)64 * SB * 4;
    int* blockSum = (int*)w;      w += (size_t)(SB + 4) * 4;
    int* blockOff = (int*)w;      w += (size_t)(SB + 4) * 4;
    int* eHist    = (int*)w;      w += (size_t)NBUK * EB * 4;
    int* eBase    = (int*)w;      w += (size_t)(NBUK * EB + 4) * 4;
    int* bo       = (int*)w;      w += (size_t)(NBUK + 4) * 4;
    w = (char*)(((size_t)w + 255) & ~(size_t)255);
    int2* ebuf    = (int2*)w;     w += (size_t)EE * 8;

    const int* srcIdx = ei;
    const int* dstIdx = ei + EE;

    // CSR: degrees + bucket counts
    zero_k<<<(NN + 255) / 256, 256, 0, stream>>>(cnt);
    histb_k<<<EB, 256, 0, stream>>>(dstIdx, cnt, eHist);
    rscan1_k<<<SB, 1024, 0, stream>>>(cnt, rowptr, dinv, blockSum);
    rscan2_k<<<1, 128, 0, stream>>>(blockSum, blockOff);
    rscan3_k<<<SB, 1024, 0, stream>>>(rowptr, blockOff);
    // bucketed edge sort -> CSR col (kills scatter write amplification)
    ebscan_k<<<1, 1024, 0, stream>>>(eHist, eBase, bo);
    ebfill_k<<<EB, 256, 0, stream>>>(srcIdx, dstIdx, eBase, ebuf);
    cfill_k<<<NBUK, 1024, 0, stream>>>(ebuf, bo, rowptr, col);
    // degree counting sort for agg load balance
    bhist2_k<<<SB, 1024, 0, stream>>>(cnt, bHist);
    bscan2_k<<<1, 1024, 0, stream>>>(bHist, bBase);
    bfill2_k<<<SB, 1024, 0, stream>>>(cnt, bBase, perm);

    // x -> fp16 + weight packing
    cvt_k<<<(NN * DIN / 8 + 255) / 256, 256, 0, stream>>>(x, xh, NN * DIN / 8);
    pack_frag_k<<<(DIN * HD + 255) / 256, 256, 0, stream>>>(Wp, WpP, DIN, HD);
    for (int i = 0; i < 3; ++i)
        pack_frag_k<<<(HD * HD + 255) / 256, 256, 0, stream>>>(Wc + (size_t)i * HD * HD,
                                                               WcP + (size_t)i * HD * HD, HD, HD);
    pack_heads_k<<<(HD * 192 + 255) / 256, 256, 0, stream>>>(relW1, rsW1, rlW1, relb1, rsb1, rlb1, W1P, b1p);

    const int gemmGrid = (NN + 63) / 64;
    const int aggGrid = (NN + 15) / 16;

    // input projection
    mgemm2_k<DIN, 0><<<gemmGrid, 256, 0, stream>>>(xh, WpP, bp, nullptr, h0);

    // layer 0
    mgemm2_k<HD, 1><<<gemmGrid, 256, 0, stream>>>(h0, WcP + 0 * HD * HD, nullptr, dinv, hws);
    agg_k<<<aggGrid, 256, 0, stream>>>(hws, h0, h1, dinv, rowptr, col, perm,
                                       bc + 0 * HD, gamma + 0 * HD, beta + 0 * HD,
                                       rmean + 0 * HD, rvar + 0 * HD, 0);
    // layer 1
    mgemm2_k<HD, 1><<<gemmGrid, 256, 0, stream>>>(h1, WcP + 1 * HD * HD, nullptr, dinv, hws);
    agg_k<<<aggGrid, 256, 0, stream>>>(hws, h1, h0, dinv, rowptr, col, perm,
                                       bc + 1 * HD, gamma + 1 * HD, beta + 1 * HD,
                                       rmean + 1 * HD, rvar + 1 * HD, 1);
    // layer 2
    mgemm2_k<HD, 1><<<gemmGrid, 256, 0, stream>>>(h0, WcP + 2 * HD * HD, nullptr, dinv, hws);
    agg_k<<<aggGrid, 256, 0, stream>>>(hws, h0, h1, dinv, rowptr, col, perm,
                                       bc + 2 * HD, gamma + 2 * HD, beta + 2 * HD,
                                       rmean + 2 * HD, rvar + 2 * HD, 1);

    // heads
    heads_k<<<(NN + 63) / 64, 256, 0, stream>>>(h1, W1P, b1p, relW2, relb2, rsW2, rsb2, rlW2, rlb2, out);
}

// Round 7
// 753.930 us; speedup vs baseline: 1.0079x; 1.0079x over previous
//
#include <hip/hip_runtime.h>
#include <hip/hip_bf16.h>
#include <math.h>

#define NN 100000
#define EE 1600000
#define DIN 384
#define HD 128
#define HHD 64
#define NRL 4
#define BN_EPS 1e-5f
#define SB 98     // scan/sort blocks: 98*1024 >= NN
#define NBUK 49   // dst buckets (dst>>11), 2048 nodes each
#define EB 391    // edge blocks: 391*4096 >= EE
#define EPB 4096  // edges per block in bucket passes
#define CPC 8     // cfill chunks per bucket

typedef _Float16 half8 __attribute__((ext_vector_type(8)));
typedef float floatx4 __attribute__((ext_vector_type(4)));

// async global->LDS 16B: LDS dest = wave-uniform base + lane*16
__device__ __forceinline__ void async_cp16(const void* g, void* l) {
    __builtin_amdgcn_global_load_lds((const __attribute__((address_space(1))) void*)g,
                                     (__attribute__((address_space(3))) void*)l, 16, 0, 0);
}

// ---------------- CSR build ----------------
__global__ void zero_k(int* __restrict__ cnt, int* __restrict__ fillc) {
    int i = blockIdx.x * blockDim.x + threadIdx.x;
    if (i < NN) { cnt[i] = 0; fillc[i] = 0; }
}

// fused: per-node degree histogram + per-(bucket,block) counts
__global__ __launch_bounds__(256) void histb_k(const int* __restrict__ dst,
                                               int* __restrict__ cnt,
                                               int* __restrict__ blockHist) {
    __shared__ int h[NBUK];
    int t = threadIdx.x;
    if (t < NBUK) h[t] = 0;
    __syncthreads();
    int base = blockIdx.x * EPB;
#pragma unroll
    for (int i = 0; i < 16; ++i) {
        int e = base + i * 256 + t;
        if (e < EE) {
            int d = dst[e];
            atomicAdd(&cnt[d], 1);
            atomicAdd(&h[d >> 11], 1);
        }
    }
    __syncthreads();
    if (t < NBUK) blockHist[t * EB + blockIdx.x] = h[t];   // bucket-major
}

// exclusive scan of NBUK*EB counts -> ebase; bucket bounds -> bo[NBUK+1]
__global__ __launch_bounds__(1024) void ebscan_k(const int* __restrict__ blockHist,
                                                 int* __restrict__ ebase,
                                                 int* __restrict__ bo) {
    __shared__ int sums[1024];
    const int TOT = NBUK * EB;
    int t = threadIdx.x;
    const int chunk = (TOT + 1023) / 1024;
    int lo = t * chunk, hi = min(lo + chunk, TOT);
    int s = 0;
    for (int i = lo; i < hi; ++i) s += blockHist[i];
    sums[t] = s;
    __syncthreads();
    for (int off = 1; off < 1024; off <<= 1) {
        int v = (t >= off) ? sums[t - off] : 0;
        __syncthreads();
        sums[t] += v;
        __syncthreads();
    }
    int run = (t == 0) ? 0 : sums[t - 1];
    for (int i = lo; i < hi; ++i) { ebase[i] = run; run += blockHist[i]; }
    __syncthreads();
    if (t < NBUK) bo[t] = ebase[t * EB];
    if (t == NBUK) bo[NBUK] = EE;
}

// scatter packed (src<<11 | dst&2047) into contiguous per-(bucket,block) streams
__global__ __launch_bounds__(256) void ebfill_k(const int* __restrict__ src,
                                                const int* __restrict__ dst,
                                                const int* __restrict__ ebase,
                                                unsigned* __restrict__ ebuf) {
    __shared__ int loff[NBUK];
    int t = threadIdx.x;
    if (t < NBUK) loff[t] = ebase[t * EB + blockIdx.x];
    __syncthreads();
    int base = blockIdx.x * EPB;
#pragma unroll
    for (int i = 0; i < 16; ++i) {
        int e = base + i * 256 + t;
        if (e < EE) {
            unsigned sv = (unsigned)src[e], d = (unsigned)dst[e];
            int p = atomicAdd(&loff[d >> 11], 1);
            ebuf[p] = (sv << 11) | (d & 2047u);
        }
    }
}

// parallel bucket fill: global fillc atomics + col writes, both L2-local per bucket
__global__ __launch_bounds__(256) void cfill_k(const unsigned* __restrict__ ebuf,
                                               const int* __restrict__ bo,
                                               const int* __restrict__ rowptr,
                                               int* __restrict__ fillc,
                                               int* __restrict__ col) {
    int b = blockIdx.x >> 3;       // bucket
    int ch = blockIdx.x & (CPC - 1);
    int lo = bo[b], hi = bo[b + 1];
    int len = hi - lo;
    int clo = lo + (int)(((long long)len * ch) >> 3);
    int chi = lo + (int)(((long long)len * (ch + 1)) >> 3);
    int nodeBase = b << 11;
    for (int j = clo + threadIdx.x; j < chi; j += 256) {
        unsigned u = ebuf[j];
        int d = nodeBase + (int)(u & 2047u);
        int p = atomicAdd(&fillc[d], 1);
        col[rowptr[d] + p] = (int)(u >> 11);
    }
}

// ---- 3-phase parallel exclusive scan of cnt -> rowptr (+dinv) ----
__global__ __launch_bounds__(1024) void rscan1_k(const int* __restrict__ cnt,
                                                 int* __restrict__ rowptr,
                                                 float* __restrict__ dinv,
                                                 int* __restrict__ blockSum) {
    __shared__ int wsum[16];
    int t = threadIdx.x;
    int i = blockIdx.x * 1024 + t;
    int v = (i < NN) ? cnt[i] : 0;
    int lane = t & 63;
    int wid = t >> 6;
    int x = v;
#pragma unroll
    for (int off = 1; off < 64; off <<= 1) {
        int y = __shfl_up(x, off, 64);
        if (lane >= off) x += y;
    }
    if (lane == 63) wsum[wid] = x;
    __syncthreads();
    if (wid == 0) {
        int s = (lane < 16) ? wsum[lane] : 0;
#pragma unroll
        for (int off = 1; off < 16; off <<= 1) {
            int y = __shfl_up(s, off, 64);
            if (lane >= off) s += y;
        }
        if (lane < 16) wsum[lane] = s;
    }
    __syncthreads();
    int excl = x - v + (wid > 0 ? wsum[wid - 1] : 0);
    if (i < NN) {
        rowptr[i] = excl;
        dinv[i] = rsqrtf((float)v + 1.0f);
    }
    if (t == 1023) blockSum[blockIdx.x] = excl + v;
}

__global__ void rscan2_k(const int* __restrict__ blockSum, int* __restrict__ blockOff) {
    __shared__ int s[SB + 1];
    int t = threadIdx.x;
    if (t < SB) s[t] = blockSum[t];
    __syncthreads();
    if (t == 0) {
        int run = 0;
        for (int i = 0; i < SB; ++i) { int c = s[i]; s[i] = run; run += c; }
        s[SB] = run;
    }
    __syncthreads();
    if (t <= SB) blockOff[t] = s[t];
}

// fused: rowptr offset add + degree-bucket LDS histogram (for counting sort)
__global__ __launch_bounds__(1024) void rscan3b_k(int* __restrict__ rowptr,
                                                  const int* __restrict__ blockOff,
                                                  const int* __restrict__ cnt,
                                                  int* __restrict__ blockHist) {
    __shared__ int h[64];
    int t = threadIdx.x;
    if (t < 64) h[t] = 0;
    __syncthreads();
    int i = blockIdx.x * 1024 + t;
    if (i < NN) {
        rowptr[i] += blockOff[blockIdx.x];
        atomicAdd(&h[min(cnt[i], 63)], 1);
    }
    if (i == 0) rowptr[NN] = blockOff[SB];
    __syncthreads();
    if (t < 64) blockHist[t * SB + blockIdx.x] = h[t];
}

__global__ __launch_bounds__(1024) void bscan2_k(const int* __restrict__ blockHist,
                                                 int* __restrict__ blockBase) {
    __shared__ int sums[1024];
    const int TOT = 64 * SB;
    int t = threadIdx.x;
    const int chunk = (TOT + 1023) / 1024;
    int lo = t * chunk, hi = min(lo + chunk, TOT);
    int s = 0;
    for (int i = lo; i < hi; ++i) s += blockHist[i];
    sums[t] = s;
    __syncthreads();
    for (int off = 1; off < 1024; off <<= 1) {
        int v = (t >= off) ? sums[t - off] : 0;
        __syncthreads();
        sums[t] += v;
        __syncthreads();
    }
    int run = (t == 0) ? 0 : sums[t - 1];
    for (int i = lo; i < hi; ++i) {
        blockBase[i] = run;
        run += blockHist[i];
    }
}

__global__ __launch_bounds__(1024) void bfill2_k(const int* __restrict__ cnt,
                                                 const int* __restrict__ blockBase,
                                                 int* __restrict__ perm) {
    __shared__ int off[64];
    int t = threadIdx.x;
    if (t < 64) off[t] = blockBase[t * SB + blockIdx.x];
    __syncthreads();
    int n = blockIdx.x * 1024 + t;
    if (n < NN) {
        int b = min(cnt[n], 63);
        int p = atomicAdd(&off[b], 1);
        perm[p] = n;
    }
}

// ---------------- pack ALL weights (Wp + 3x Wc) into MFMA fragment layout fp16 ----------------
// frag element t = ((kc*NT + nt)*64 + lane)*8 + j  holds  B[kc*32 + (lane>>4)*8 + j][nt*16 + (lane&15)]
__global__ void packall_k(const float* __restrict__ Wp, const float* __restrict__ Wc,
                          _Float16* __restrict__ WpP, _Float16* __restrict__ WcP) {
    int t = blockIdx.x * blockDim.x + threadIdx.x;
    const float* B;
    _Float16* out;
    int idx;
    if (t < DIN * HD) { B = Wp; out = WpP; idx = t; }
    else {
        int r = t - DIN * HD;
        if (r >= 3 * HD * HD) return;
        int layer = r / (HD * HD);
        idx = r - layer * HD * HD;
        B = Wc + (size_t)layer * HD * HD;
        out = WcP + (size_t)layer * HD * HD;
    }
    int j = idx & 7;
    int lane = (idx >> 3) & 63;
    int rest = idx >> 9;
    const int NT = 8;             // N=128
    int nt = rest % NT;
    int kc = rest / NT;
    int k = kc * 32 + (lane >> 4) * 8 + j;
    int c = nt * 16 + (lane & 15);
    out[idx] = (_Float16)B[(size_t)k * HD + c];
}

// pack the three head W1s into frag layout for N=192, plus bias
__global__ void pack_heads_k(const float* __restrict__ relW1, const float* __restrict__ rsW1,
                             const float* __restrict__ rlW1, const float* __restrict__ relb1,
                             const float* __restrict__ rsb1, const float* __restrict__ rlb1,
                             _Float16* __restrict__ out, float* __restrict__ b1p) {
    int t = blockIdx.x * blockDim.x + threadIdx.x;
    if (t < HD * 192) {
        int j = t & 7;
        int lane = (t >> 3) & 63;
        int rest = t >> 9;
        const int NT = 12;
        int nt = rest % NT;
        int kc = rest / NT;
        int k = kc * 32 + (lane >> 4) * 8 + j;
        int c = nt * 16 + (lane & 15);
        int s = c >> 6, jj = c & 63;
        float v = (s == 0) ? relW1[k * HHD + jj] : (s == 1) ? rsW1[k * HHD + jj] : rlW1[k * HHD + jj];
        out[t] = (_Float16)v;
    }
    if (t < 192) {
        int s = t >> 6, jj = t & 63;
        b1p[t] = (s == 0) ? relb1[jj] : (s == 1) ? rsb1[jj] : rlb1[jj];
    }
}

// ---------------- input projection: fp32 A staged via async LDS, fp16 MFMA ----------------
// h0 = relu(x @ Wp + bp). LDS: 64 rows x 64 fp32, chunk (16B=4 floats) s holds
// global chunk (s ^ (row&15)) -> conflict-free b128 reads + lane*16 dest rule.
__global__ __launch_bounds__(256) void mgemmx_k(const float* __restrict__ A,
                                                const _Float16* __restrict__ Bp,
                                                const float* __restrict__ bias,
                                                _Float16* __restrict__ C) {
    constexpr int K = DIN;
    constexpr int NC = K / 64;       // 6
    const int NT = 8;
    __shared__ float As[2][64 * 64]; // 2 x 16 KB
    const int tid = threadIdx.x;
    const int w = tid >> 6;
    const int L = tid & 63;
    const int q = L >> 4;
    const int l16 = L & 15;
    const int row0 = blockIdx.x * 64;

    // staging geometry: inst i stages rows w*16+i*4+(L>>4), fetching chunk (L&15)^(row&15)
    size_t gbase[4];
    float* lb0[4];
    float* lb1[4];
#pragma unroll
    for (int i = 0; i < 4; ++i) {
        int r = w * 16 + i * 4 + (L >> 4);
        int c = (L & 15) ^ (r & 15);
        gbase[i] = (size_t)min(row0 + r, NN - 1) * K + c * 4;
        lb0[i] = &As[0][(w * 16 + i * 4) * 64];
        lb1[i] = &As[1][(w * 16 + i * 4) * 64];
    }

    floatx4 acc[NT];
#pragma unroll
    for (int nt = 0; nt < NT; ++nt) acc[nt] = (floatx4){0.f, 0.f, 0.f, 0.f};

    const half8* __restrict__ bp8 = (const half8*)Bp;
    const int rr = w * 16 + l16;       // row this lane computes
    const int rbase = rr * 64;
    const int rx = rr & 15;

#pragma unroll
    for (int i = 0; i < 4; ++i) async_cp16(A + gbase[i], lb0[i]);
    __syncthreads();

    for (int kc = 0; kc < NC; ++kc) {
        if (kc + 1 < NC) {
            if ((kc & 1) == 0) {
#pragma unroll
                for (int i = 0; i < 4; ++i) async_cp16(A + gbase[i] + (kc + 1) * 64, lb1[i]);
            } else {
#pragma unroll
                for (int i = 0; i < 4; ++i) async_cp16(A + gbase[i] + (kc + 1) * 64, lb0[i]);
            }
        }
        const float* cur = As[kc & 1];
#pragma unroll
        for (int kk = 0; kk < 2; ++kk) {
            int cb = kk * 8 + 2 * q;
            float4 f0 = *(const float4*)(cur + rbase + ((cb ^ rx) * 4));
            float4 f1 = *(const float4*)(cur + rbase + (((cb + 1) ^ rx) * 4));
            half8 a = {(_Float16)f0.x, (_Float16)f0.y, (_Float16)f0.z, (_Float16)f0.w,
                       (_Float16)f1.x, (_Float16)f1.y, (_Float16)f1.z, (_Float16)f1.w};
#pragma unroll
            for (int nt = 0; nt < NT; ++nt) {
                half8 b = bp8[(size_t)((kc * 2 + kk) * NT + nt) * 64 + L];
                acc[nt] = __builtin_amdgcn_mfma_f32_16x16x32_f16(a, b, acc[nt], 0, 0, 0);
            }
        }
        __syncthreads();
    }

#pragma unroll
    for (int r = 0; r < 4; ++r) {
        int row = row0 + w * 16 + q * 4 + r;
        if (row >= NN) continue;
#pragma unroll
        for (int nt = 0; nt < NT; ++nt) {
            int c = nt * 16 + l16;
            C[(size_t)row * HD + c] = (_Float16)fmaxf(acc[nt][r] + bias[c], 0.f);
        }
    }
}

// ---------------- MFMA GEMM (fp16 A) with async-LDS double buffer ----------------
template<int K, int MODE>
__global__ __launch_bounds__(256) void mgemm2_k(const _Float16* __restrict__ A,
                                                const _Float16* __restrict__ Bp,
                                                const float* __restrict__ bias,
                                                const float* __restrict__ dinv,
                                                _Float16* __restrict__ C) {
    constexpr int NC = K / 64;
    const int NT = 8;
    __shared__ _Float16 As[2][64 * 64];
    const int tid = threadIdx.x;
    const int w = tid >> 6;
    const int L = tid & 63;
    const int q = L >> 4;
    const int l16 = L & 15;
    const int row0 = blockIdx.x * 64;

    const int r8 = L >> 3;
    const int scol = ((L & 7) ^ r8) * 8;
    const size_t srow0 = (size_t)min(row0 + w * 8 + r8, NN - 1) * K;
    const size_t srow1 = (size_t)min(row0 + 32 + w * 8 + r8, NN - 1) * K;
    _Float16* lds0a = &As[0][w * 512];
    _Float16* lds0b = &As[0][(4 + w) * 512];
    _Float16* lds1a = &As[1][w * 512];
    _Float16* lds1b = &As[1][(4 + w) * 512];

    floatx4 acc[NT];
#pragma unroll
    for (int nt = 0; nt < NT; ++nt) acc[nt] = (floatx4){0.f, 0.f, 0.f, 0.f};

    const half8* __restrict__ bp8 = (const half8*)Bp;
    const int rs = l16 & 7;
    const int gsel = (w * 2 + (l16 >> 3)) * 512 + rs * 64;

    async_cp16(A + srow0 + scol, lds0a);
    async_cp16(A + srow1 + scol, lds0b);
    __syncthreads();

    for (int kc = 0; kc < NC; ++kc) {
        if (kc + 1 < NC) {
            if ((kc & 1) == 0) {
                async_cp16(A + srow0 + (kc + 1) * 64 + scol, lds1a);
                async_cp16(A + srow1 + (kc + 1) * 64 + scol, lds1b);
            } else {
                async_cp16(A + srow0 + (kc + 1) * 64 + scol, lds0a);
                async_cp16(A + srow1 + (kc + 1) * 64 + scol, lds0b);
            }
        }
        const _Float16* cur = As[kc & 1];
#pragma unroll
        for (int kk = 0; kk < 2; ++kk) {
            int chunk = kk * 4 + q;
            half8 a = *(const half8*)(cur + gsel + ((chunk ^ rs) * 8));
#pragma unroll
            for (int nt = 0; nt < NT; ++nt) {
                half8 b = bp8[(size_t)((kc * 2 + kk) * NT + nt) * 64 + L];
                acc[nt] = __builtin_amdgcn_mfma_f32_16x16x32_f16(a, b, acc[nt], 0, 0, 0);
            }
        }
        __syncthreads();
    }

#pragma unroll
    for (int r = 0; r < 4; ++r) {
        int row = row0 + w * 16 + q * 4 + r;
        if (row >= NN) continue;
        if (MODE == 0) {
#pragma unroll
            for (int nt = 0; nt < NT; ++nt) {
                int c = nt * 16 + l16;
                C[(size_t)row * HD + c] = (_Float16)fmaxf(acc[nt][r] + bias[c], 0.f);
            }
        } else {
            float dv = dinv[row];
#pragma unroll
            for (int nt = 0; nt < NT; ++nt) {
                int c = nt * 16 + l16;
                C[(size_t)row * HD + c] = (_Float16)(acc[nt][r] * dv);
            }
        }
    }
}

// ---------------- aggregation + BN + relu + residual (fp16 gather, 8-deep) ----------------
__global__ __launch_bounds__(256) void agg_k(const _Float16* __restrict__ hws,
                                             const _Float16* __restrict__ h_in,
                                             _Float16* __restrict__ h_out,
                                             const float* __restrict__ dinv,
                                             const int* __restrict__ rowptr,
                                             const int* __restrict__ col,
                                             const int* __restrict__ perm,
                                             const float* __restrict__ bcv,
                                             const float* __restrict__ gamma,
                                             const float* __restrict__ beta,
                                             const float* __restrict__ rmean,
                                             const float* __restrict__ rvar,
                                             int residual) {
    int g = blockIdx.x * 16 + (threadIdx.x >> 4);
    if (g >= NN) return;
    int node = perm[g];
    int l = threadIdx.x & 15;
    int f0 = l * 8;

    int lo = rowptr[node], hi = rowptr[node + 1];

    half8 vself = *(const half8*)(hws + (size_t)node * HD + f0);
    half8 hin;
    if (residual) hin = *(const half8*)(h_in + (size_t)node * HD + f0);

    float acc[8];
#pragma unroll
    for (int i = 0; i < 8; ++i) acc[i] = 0.f;

    int j = lo;
    for (; j + 7 < hi; j += 8) {
        half8 v0 = *(const half8*)(hws + (size_t)col[j]     * HD + f0);
        half8 v1 = *(const half8*)(hws + (size_t)col[j + 1] * HD + f0);
        half8 v2 = *(const half8*)(hws + (size_t)col[j + 2] * HD + f0);
        half8 v3 = *(const half8*)(hws + (size_t)col[j + 3] * HD + f0);
        half8 v4 = *(const half8*)(hws + (size_t)col[j + 4] * HD + f0);
        half8 v5 = *(const half8*)(hws + (size_t)col[j + 5] * HD + f0);
        half8 v6 = *(const half8*)(hws + (size_t)col[j + 6] * HD + f0);
        half8 v7 = *(const half8*)(hws + (size_t)col[j + 7] * HD + f0);
#pragma unroll
        for (int i = 0; i < 8; ++i)
            acc[i] += (((float)v0[i] + (float)v1[i]) + ((float)v2[i] + (float)v3[i])) +
                      (((float)v4[i] + (float)v5[i]) + ((float)v6[i] + (float)v7[i]));
    }
    for (; j + 3 < hi; j += 4) {
        half8 v0 = *(const half8*)(hws + (size_t)col[j]     * HD + f0);
        half8 v1 = *(const half8*)(hws + (size_t)col[j + 1] * HD + f0);
        half8 v2 = *(const half8*)(hws + (size_t)col[j + 2] * HD + f0);
        half8 v3 = *(const half8*)(hws + (size_t)col[j + 3] * HD + f0);
#pragma unroll
        for (int i = 0; i < 8; ++i)
            acc[i] += ((float)v0[i] + (float)v1[i]) + ((float)v2[i] + (float)v3[i]);
    }
    for (; j < hi; ++j) {
        half8 v0 = *(const half8*)(hws + (size_t)col[j] * HD + f0);
#pragma unroll
        for (int i = 0; i < 8; ++i) acc[i] += (float)v0[i];
    }
#pragma unroll
    for (int i = 0; i < 8; ++i) acc[i] += (float)vself[i];

    float dv = dinv[node];
    half8 outv;
#pragma unroll
    for (int i = 0; i < 8; ++i) {
        int f = f0 + i;
        float pre = dv * acc[i] + bcv[f];
        float scale = gamma[f] * rsqrtf(rvar[f] + BN_EPS);
        float v = (pre - rmean[f]) * scale + beta[f];
        v = fmaxf(v, 0.f);
        if (residual) v += (float)hin[i];
        outv[i] = (_Float16)v;
    }
    *(half8*)(h_out + (size_t)node * HD + f0) = outv;
}

// ---------------- fused heads ----------------
__global__ __launch_bounds__(256) void heads_k(const _Float16* __restrict__ hfin,
                                               const _Float16* __restrict__ W1P,
                                               const float* __restrict__ b1p,
                                               const float* __restrict__ relW2, const float* __restrict__ relb2,
                                               const float* __restrict__ rsW2,  const float* __restrict__ rsb2,
                                               const float* __restrict__ rlW2,  const float* __restrict__ rlb2,
                                               float* __restrict__ out) {
    __shared__ float Hs[64 * 196];
#define HS(r, c) Hs[(r) * 196 + (c)]
    const int NT = 12;
    const int tid = threadIdx.x;
    const int w = tid >> 6;
    const int L = tid & 63;
    const int q = L >> 4;
    const int l16 = L & 15;
    const int row0 = blockIdx.x * 64 + w * 16;

    floatx4 acc[NT];
#pragma unroll
    for (int nt = 0; nt < NT; ++nt) acc[nt] = (floatx4){0.f, 0.f, 0.f, 0.f};

    const half8* __restrict__ bp8 = (const half8*)W1P;
    const half8 hz = {(_Float16)0, (_Float16)0, (_Float16)0, (_Float16)0,
                      (_Float16)0, (_Float16)0, (_Float16)0, (_Float16)0};
    const int r0 = row0 + l16;

#pragma unroll
    for (int kc = 0; kc < HD / 32; ++kc) {
        half8 a = (r0 < NN) ? *(const half8*)(hfin + (size_t)r0 * HD + kc * 32 + q * 8) : hz;
#pragma unroll
        for (int nt = 0; nt < NT; ++nt) {
            half8 b = bp8[(size_t)(kc * NT + nt) * 64 + L];
            acc[nt] = __builtin_amdgcn_mfma_f32_16x16x32_f16(a, b, acc[nt], 0, 0, 0);
        }
    }

#pragma unroll
    for (int nt = 0; nt < NT; ++nt) {
        int c = nt * 16 + l16;
        float bb = b1p[c];
#pragma unroll
        for (int r = 0; r < 4; ++r)
            HS(w * 16 + q * 4 + r, c) = fmaxf(acc[nt][r] + bb, 0.f);
    }
    __syncthreads();

    for (int t = tid; t < 64 * 6; t += 256) {
        int row = t & 63;
        int o = t >> 6;
        int grow = blockIdx.x * 64 + row;
        if (grow >= NN) continue;
        if (o == 0) {
            float s = 0.f;
#pragma unroll
            for (int jj = 0; jj < 64; ++jj) s += HS(row, 64 + jj) * rsW2[jj];
            out[grow] = 1.f / (1.f + expf(-(s + rsb2[0])));
        } else if (o <= 4) {
            int c = o - 1;
            float s = 0.f;
#pragma unroll
            for (int jj = 0; jj < 64; ++jj) s += HS(row, 128 + jj) * rlW2[jj * NRL + c];
            out[NN + (size_t)grow * NRL + c] = s + rlb2[c];
        } else {
            float s = 0.f;
#pragma unroll
            for (int jj = 0; jj < 64; ++jj) s += HS(row, jj) * relW2[jj];
            out[NN * (1 + NRL) + grow] = 1.f / (1.f + expf(-(s + relb2[0])));
        }
    }
#undef HS
}

extern "C" void kernel_launch(void* const* d_in, const int* in_sizes, int n_in,
                              void* d_out, int out_size, void* d_ws, size_t ws_size,
                              hipStream_t stream) {
    const float* x     = (const float*)d_in[0];
    const int*   ei    = (const int*)d_in[1];
    const float* Wp    = (const float*)d_in[2];
    const float* bp    = (const float*)d_in[3];
    const float* Wc    = (const float*)d_in[4];
    const float* bc    = (const float*)d_in[5];
    const float* gamma = (const float*)d_in[6];
    const float* beta  = (const float*)d_in[7];
    const float* rmean = (const float*)d_in[8];
    const float* rvar  = (const float*)d_in[9];
    const float* relW1 = (const float*)d_in[10];
    const float* relb1 = (const float*)d_in[11];
    const float* relW2 = (const float*)d_in[12];
    const float* relb2 = (const float*)d_in[13];
    const float* rsW1  = (const float*)d_in[14];
    const float* rsb1  = (const float*)d_in[15];
    const float* rsW2  = (const float*)d_in[16];
    const float* rsb2  = (const float*)d_in[17];
    const float* rlW1  = (const float*)d_in[18];
    const float* rlb1  = (const float*)d_in[19];
    const float* rlW2  = (const float*)d_in[20];
    const float* rlb2  = (const float*)d_in[21];
    float* out = (float*)d_out;

    char* w = (char*)d_ws;
    _Float16* h0  = (_Float16*)w; w += (size_t)NN * HD * 2;
    _Float16* h1  = (_Float16*)w; w += (size_t)NN * HD * 2;
    _Float16* hws = (_Float16*)w; w += (size_t)NN * HD * 2;
    _Float16* WpP = (_Float16*)w; w += (size_t)DIN * HD * 2;
    _Float16* WcP = (_Float16*)w; w += (size_t)3 * HD * HD * 2;
    _Float16* W1P = (_Float16*)w; w += (size_t)HD * 192 * 2;
    float* b1p    = (float*)w;    w += 256 * 4;
    float* dinv   = (float*)w;    w += (size_t)NN * 4;
    int* rowptr   = (int*)w;      w += (size_t)(NN + 4) * 4;
    int* col      = (int*)w;      w += (size_t)EE * 4;
    int* cnt      = (int*)w;      w += (size_t)NN * 4;
    int* fillc    = (int*)w;      w += (size_t)NN * 4;
    int* perm     = (int*)w;      w += (size_t)NN * 4;
    int* bHist    = (int*)w;      w += (size_t)64 * SB * 4;
    int* bBase    = (int*)w;      w += (size_t)64 * SB * 4;
    int* blockSum = (int*)w;      w += (size_t)(SB + 4) * 4;
    int* blockOff = (int*)w;      w += (size_t)(SB + 4) * 4;
    int* eHist    = (int*)w;      w += (size_t)NBUK * EB * 4;
    int* eBase    = (int*)w;      w += (size_t)(NBUK * EB + 4) * 4;
    int* bo       = (int*)w;      w += (size_t)(NBUK + 4) * 4;
    w = (char*)(((size_t)w + 255) & ~(size_t)255);
    unsigned* ebuf = (unsigned*)w; w += (size_t)EE * 4;

    const int* srcIdx = ei;
    const int* dstIdx = ei + EE;

    // CSR: degrees + bucket counts
    zero_k<<<(NN + 255) / 256, 256, 0, stream>>>(cnt, fillc);
    histb_k<<<EB, 256, 0, stream>>>(dstIdx, cnt, eHist);
    rscan1_k<<<SB, 1024, 0, stream>>>(cnt, rowptr, dinv, blockSum);
    rscan2_k<<<1, 128, 0, stream>>>(blockSum, blockOff);
    rscan3b_k<<<SB, 1024, 0, stream>>>(rowptr, blockOff, cnt, bHist);
    // bucketed edge sort -> CSR col (packed 4B entries, L2-local fill)
    ebscan_k<<<1, 1024, 0, stream>>>(eHist, eBase, bo);
    ebfill_k<<<EB, 256, 0, stream>>>(srcIdx, dstIdx, eBase, ebuf);
    cfill_k<<<NBUK * CPC, 256, 0, stream>>>(ebuf, bo, rowptr, fillc, col);
    // degree counting sort for agg load balance
    bscan2_k<<<1, 1024, 0, stream>>>(bHist, bBase);
    bfill2_k<<<SB, 1024, 0, stream>>>(cnt, bBase, perm);

    // weight packing
    packall_k<<<(DIN * HD + 3 * HD * HD + 255) / 256, 256, 0, stream>>>(Wp, Wc, WpP, WcP);
    pack_heads_k<<<(HD * 192 + 255) / 256, 256, 0, stream>>>(relW1, rsW1, rlW1, relb1, rsb1, rlb1, W1P, b1p);

    const int gemmGrid = (NN + 63) / 64;
    const int aggGrid = (NN + 15) / 16;

    // input projection: fp32 x read directly (no cvt pass)
    mgemmx_k<<<gemmGrid, 256, 0, stream>>>(x, WpP, bp, h0);

    // layer 0
    mgemm2_k<HD, 1><<<gemmGrid, 256, 0, stream>>>(h0, WcP + 0 * HD * HD, nullptr, dinv, hws);
    agg_k<<<aggGrid, 256, 0, stream>>>(hws, h0, h1, dinv, rowptr, col, perm,
                                       bc + 0 * HD, gamma + 0 * HD, beta + 0 * HD,
                                       rmean + 0 * HD, rvar + 0 * HD, 0);
    // layer 1
    mgemm2_k<HD, 1><<<gemmGrid, 256, 0, stream>>>(h1, WcP + 1 * HD * HD, nullptr, dinv, hws);
    agg_k<<<aggGrid, 256, 0, stream>>>(hws, h1, h0, dinv, rowptr, col, perm,
                                       bc + 1 * HD, gamma + 1 * HD, beta + 1 * HD,
                                       rmean + 1 * HD, rvar + 1 * HD, 1);
    // layer 2
    mgemm2_k<HD, 1><<<gemmGrid, 256, 0, stream>>>(h0, WcP + 2 * HD * HD, nullptr, dinv, hws);
    agg_k<<<aggGrid, 256, 0, stream>>>(hws, h0, h1, dinv, rowptr, col, perm,
                                       bc + 2 * HD, gamma + 2 * HD, beta + 2 * HD,
                                       rmean + 2 * HD, rvar + 2 * HD, 1);

    // heads
    heads_k<<<(NN + 63) / 64, 256, 0, stream>>>(h1, W1P, b1p, relW2, relb2, rsW2, rsb2, rlW2, rlb2, out);
}